// Round 1
// baseline (162.701 us; speedup 1.0000x reference)
//
#include <hip/hip_runtime.h>
#include <hip/hip_bf16.h>

// Problem constants: B=128, V=1024, D=512.
// Pipeline:
//   prep:    f32->bf16 converts (feat/proto/W1), zipf ranks->zw + zwsum, row inv-norms
//   gemm3:   bf16 MFMA: fp=feat@Wf^T (f32), ppbT=Wp@proto^T+b1 (bf16, pre-transposed), dotraw=feat@proto^T (f32)
//   hs:      hs[b,v] = sum_k relu(fp[b,k]+ppbT[k,v])*W2[k]   (f32 VALU, k-split 2)
//   combine: w = (zw/zwsum)*(1+sim)*sigmoid(hs+b2); softmax over v

typedef __attribute__((ext_vector_type(8))) short bhalf8;
typedef __attribute__((ext_vector_type(4))) float f32x4;

static __device__ __forceinline__ unsigned short f2bf(float x) {
    union { __hip_bfloat16 h; unsigned short u; } cv;
    cv.h = __float2bfloat16(x);
    return cv.u;
}

static __device__ __forceinline__ float2 bf2x2_to_f2(unsigned int u) {
    float2 r;
    r.x = __uint_as_float(u << 16);
    r.y = __uint_as_float(u & 0xffff0000u);
    return r;
}

// ---------------- prep: cvt (blocks 0..511), zipf (512..527), norms (528..815) ---------------
__global__ __launch_bounds__(256) void prep_kernel(
    const float* __restrict__ feat, const float* __restrict__ counts,
    const float* __restrict__ proto, const float* __restrict__ zs,
    const float* __restrict__ W1,
    unsigned short* __restrict__ feat_bf, unsigned short* __restrict__ proto_bf,
    unsigned short* __restrict__ w1_bf,
    float* __restrict__ zw, float* __restrict__ zwsum,
    float* __restrict__ invf, float* __restrict__ invp)
{
    int bx = blockIdx.x, tid = threadIdx.x;
    if (bx < 512) {
        // convert 278528 float4 vectors: feat(16384), proto(131072), W1(131072)
        const int NV = 16384 + 131072 + 131072;
        for (int i = bx * 256 + tid; i < NV; i += 512 * 256) {
            float4 f;
            unsigned short* dst;
            if (i < 16384) {
                f = ((const float4*)feat)[i];
                dst = feat_bf + (size_t)i * 4;
            } else if (i < 147456) {
                int j = i - 16384;
                f = ((const float4*)proto)[j];
                dst = proto_bf + (size_t)j * 4;
            } else {
                int j = i - 147456;
                f = ((const float4*)W1)[j];
                dst = w1_bf + (size_t)j * 4;
            }
            ushort4 o;
            o.x = f2bf(f.x); o.y = f2bf(f.y); o.z = f2bf(f.z); o.w = f2bf(f.w);
            *(ushort4*)dst = o;
        }
    } else if (bx < 528) {
        // zipf: block handles 64 i's; 4 threads per i, each scans a quarter of j
        __shared__ float cn[1024];
        __shared__ float zacc[64];
        ((float4*)cn)[tid] = ((const float4*)counts)[tid];
        __syncthreads();
        int il = tid >> 2, q = tid & 3;
        int i = (bx - 512) * 64 + il;
        float ci = cn[i];
        int cnt = 0;
        int j0 = q * 256;
        for (int j = j0; j < j0 + 256; ++j) {
            float cj = cn[j];
            cnt += (cj > ci) ? 1 : 0;
            cnt += (cj == ci && j < i) ? 1 : 0;   // stable tie-break: earlier index ranks first
        }
        cnt += __shfl_xor(cnt, 1);
        cnt += __shfl_xor(cnt, 2);
        if (q == 0) {
            float s = zs[0];
            float zv = powf((float)(cnt + 1), -s);
            zw[i] = zv;
            zacc[il] = zv;
        }
        __syncthreads();
        if (tid < 64) {
            float x = zacc[tid];
            for (int o = 32; o; o >>= 1) x += __shfl_xor(x, o);
            if (tid == 0) atomicAdd(zwsum, x);
        }
    } else {
        // inverse L2 norms: 4 rows per block, one wave per row (rows 0..127 feat, 128..1151 proto)
        int nb = bx - 528;
        int w = tid >> 6, lane = tid & 63;
        int row = nb * 4 + w;
        const float* src = (row < 128) ? (feat + (size_t)row * 512)
                                       : (proto + (size_t)(row - 128) * 512);
        const float4* rp = (const float4*)src;
        float4 a = rp[lane * 2], b = rp[lane * 2 + 1];
        float ss = a.x*a.x + a.y*a.y + a.z*a.z + a.w*a.w
                 + b.x*b.x + b.y*b.y + b.z*b.z + b.w*b.w;
        for (int o = 32; o; o >>= 1) ss += __shfl_xor(ss, o);
        if (lane == 0) {
            float inv = 1.0f / fmaxf(sqrtf(ss), 1e-12f);
            if (row < 128) invf[row] = inv; else invp[row - 128] = inv;
        }
    }
}

// ---------------- gemm3: three bf16 GEMMs, 64x64 tiles, BK=32 ----------------
// blocks [0,16): fp = feat @ Wf^T        M=128 N=512  C f32
// blocks [16,144): ppbT = Wp @ proto^T + b1  M=512 N=1024 C bf16 (bias per row)
// blocks [144,176): dotraw = feat @ proto^T  M=128 N=1024 C f32
__global__ __launch_bounds__(256) void gemm3_kernel(
    const unsigned short* __restrict__ feat_bf, const unsigned short* __restrict__ proto_bf,
    const unsigned short* __restrict__ w1_bf, const float* __restrict__ b1,
    float* __restrict__ fp, unsigned short* __restrict__ ppbT, float* __restrict__ dotraw)
{
    int bx = blockIdx.x, tid = threadIdx.x;
    const unsigned short* A; const unsigned short* Bm;
    int lda, ldb, ldc, tm, tn;
    float* Cf = nullptr; unsigned short* Cb = nullptr; const float* bias = nullptr;
    if (bx < 16) {
        A = feat_bf; lda = 512; Bm = w1_bf; ldb = 1024; Cf = fp; ldc = 512;
        tm = bx >> 3; tn = bx & 7;
    } else if (bx < 144) {
        int t = bx - 16;
        A = w1_bf + 512; lda = 1024; Bm = proto_bf; ldb = 512; Cb = ppbT; ldc = 1024; bias = b1;
        tm = t >> 4; tn = t & 15;
    } else {
        int t = bx - 144;
        A = feat_bf; lda = 512; Bm = proto_bf; ldb = 512; Cf = dotraw; ldc = 1024;
        tm = t >> 4; tn = t & 15;
    }

    __shared__ unsigned short As[64 * 40];   // stride 40 halfs (80B): max 2-way bank alias = free
    __shared__ unsigned short Bs[64 * 40];

    int r = tid >> 2, kq = (tid & 3) * 8;
    int wave = tid >> 6, lane = tid & 63;
    int fr = lane & 15, quad = lane >> 4;

    const unsigned short* Ag = A + (size_t)(tm * 64 + r) * lda + kq;
    const unsigned short* Bg = Bm + (size_t)(tn * 64 + r) * ldb + kq;

    f32x4 acc0 = {0.f, 0.f, 0.f, 0.f};
    f32x4 acc1 = acc0, acc2 = acc0, acc3 = acc0;

    for (int kc = 0; kc < 512; kc += 32) {
        int4 av = *(const int4*)(Ag + kc);
        int4 bv = *(const int4*)(Bg + kc);
        __syncthreads();
        *(int4*)&As[r * 40 + kq] = av;
        *(int4*)&Bs[r * 40 + kq] = bv;
        __syncthreads();
        bhalf8 af  = *(const bhalf8*)&As[(wave * 16 + fr) * 40 + quad * 8];
        bhalf8 bf0 = *(const bhalf8*)&Bs[(fr) * 40 + quad * 8];
        bhalf8 bf1 = *(const bhalf8*)&Bs[(16 + fr) * 40 + quad * 8];
        bhalf8 bf2 = *(const bhalf8*)&Bs[(32 + fr) * 40 + quad * 8];
        bhalf8 bf3 = *(const bhalf8*)&Bs[(48 + fr) * 40 + quad * 8];
        acc0 = __builtin_amdgcn_mfma_f32_16x16x32_bf16(af, bf0, acc0, 0, 0, 0);
        acc1 = __builtin_amdgcn_mfma_f32_16x16x32_bf16(af, bf1, acc1, 0, 0, 0);
        acc2 = __builtin_amdgcn_mfma_f32_16x16x32_bf16(af, bf2, acc2, 0, 0, 0);
        acc3 = __builtin_amdgcn_mfma_f32_16x16x32_bf16(af, bf3, acc3, 0, 0, 0);
    }

    // C/D layout: col = lane&15, row = quad*4 + reg  [measured m89/m91]
    int m0 = tm * 64 + wave * 16 + quad * 4;
    int n0 = tn * 64 + fr;
    f32x4 accs[4] = {acc0, acc1, acc2, acc3};
    if (Cf) {
        for (int j = 0; j < 4; ++j)
            for (int rr = 0; rr < 4; ++rr)
                Cf[(size_t)(m0 + rr) * ldc + n0 + j * 16] = accs[j][rr];
    } else {
        float bv4[4];
        for (int rr = 0; rr < 4; ++rr) bv4[rr] = bias[m0 + rr];
        for (int j = 0; j < 4; ++j)
            for (int rr = 0; rr < 4; ++rr)
                Cb[(size_t)(m0 + rr) * ldc + n0 + j * 16] = f2bf(accs[j][rr] + bv4[rr]);
    }
}

// ---------------- hs: hs[b,v] = sum_k relu(fp[b,k]+ppbT[k,v])*W2[k], k-split 2 -------------
// grid 256: bgroup(64) x vhalf(2) x khalf(2); 256 thr, thread = 2 b's x 2 v's
__global__ __launch_bounds__(256) void hs_kernel(
    const float* __restrict__ fp, const unsigned short* __restrict__ ppbT,
    const float* __restrict__ W2, float* __restrict__ hsp)
{
    int bx = blockIdx.x, tid = threadIdx.x;
    int bg = bx & 63, vh = (bx >> 6) & 1, kh = bx >> 7;
    int b0 = bg * 2;
    int v = vh * 512 + tid * 2;
    const float* fp0 = fp + (size_t)b0 * 512;
    const float* fp1 = fp0 + 512;
    float a00 = 0.f, a01 = 0.f, a10 = 0.f, a11 = 0.f;
    int k0 = kh * 256;
    #pragma unroll 4
    for (int k = k0; k < k0 + 256; ++k) {
        unsigned int u = *(const unsigned int*)(ppbT + (size_t)k * 1024 + v);
        float2 p = bf2x2_to_f2(u);
        float w2k = W2[k];           // wave-uniform -> scalar load
        float f0 = fp0[k], f1 = fp1[k];
        a00 += fmaxf(f0 + p.x, 0.f) * w2k;
        a01 += fmaxf(f0 + p.y, 0.f) * w2k;
        a10 += fmaxf(f1 + p.x, 0.f) * w2k;
        a11 += fmaxf(f1 + p.y, 0.f) * w2k;
    }
    float* o = hsp + (size_t)(kh * 128 + b0) * 1024 + v;
    *(float2*)o = make_float2(a00, a01);
    *(float2*)(o + 1024) = make_float2(a10, a11);
}

// ---------------- combine + softmax: one block per b ----------------
__global__ __launch_bounds__(256) void combine_kernel(
    const float* __restrict__ dotraw, const float* __restrict__ hsp,
    const float* __restrict__ zw, const float* __restrict__ zwsum,
    const float* __restrict__ invf, const float* __restrict__ invp,
    const float* __restrict__ temp, const float* __restrict__ b2,
    float* __restrict__ out)
{
    int b = blockIdx.x, tid = threadIdx.x;
    int wave = tid >> 6, lane = tid & 63;
    int v = tid * 4;
    __shared__ float red[4];

    float it  = invf[b] / fmaxf(temp[0], 1e-4f);
    float izw = 1.0f / fmaxf(zwsum[0], 1e-8f);
    float b2v = b2[0];

    float4 dr  = *(const float4*)(dotraw + (size_t)b * 1024 + v);
    float4 h0  = *(const float4*)(hsp + (size_t)b * 1024 + v);
    float4 h1  = *(const float4*)(hsp + (size_t)(128 + b) * 1024 + v);
    float4 zw4 = *(const float4*)(zw + v);
    float4 ip4 = *(const float4*)(invp + v);

    float4 w;
    {
        float s0 = dr.x * it * ip4.x, s1 = dr.y * it * ip4.y;
        float s2 = dr.z * it * ip4.z, s3 = dr.w * it * ip4.w;
        float g0 = h0.x + h1.x + b2v, g1 = h0.y + h1.y + b2v;
        float g2 = h0.z + h1.z + b2v, g3 = h0.w + h1.w + b2v;
        w.x = (zw4.x * izw) * (1.0f + s0) * (1.0f / (1.0f + expf(-g0)));
        w.y = (zw4.y * izw) * (1.0f + s1) * (1.0f / (1.0f + expf(-g1)));
        w.z = (zw4.z * izw) * (1.0f + s2) * (1.0f / (1.0f + expf(-g2)));
        w.w = (zw4.w * izw) * (1.0f + s3) * (1.0f / (1.0f + expf(-g3)));
    }

    float mx = fmaxf(fmaxf(w.x, w.y), fmaxf(w.z, w.w));
    for (int o = 32; o; o >>= 1) mx = fmaxf(mx, __shfl_xor(mx, o));
    if (lane == 0) red[wave] = mx;
    __syncthreads();
    mx = fmaxf(fmaxf(red[0], red[1]), fmaxf(red[2], red[3]));

    float4 e;
    e.x = expf(w.x - mx); e.y = expf(w.y - mx);
    e.z = expf(w.z - mx); e.w = expf(w.w - mx);
    float sm = e.x + e.y + e.z + e.w;
    for (int o = 32; o; o >>= 1) sm += __shfl_xor(sm, o);
    __syncthreads();            // red[] reuse
    if (lane == 0) red[wave] = sm;
    __syncthreads();
    float inv = 1.0f / (red[0] + red[1] + red[2] + red[3]);

    float4 r4;
    r4.x = e.x * inv; r4.y = e.y * inv; r4.z = e.z * inv; r4.w = e.w * inv;
    *(float4*)(out + (size_t)b * 1024 + v) = r4;
}

// ---------------- launch ----------------
extern "C" void kernel_launch(void* const* d_in, const int* in_sizes, int n_in,
                              void* d_out, int out_size, void* d_ws, size_t ws_size,
                              hipStream_t stream) {
    const float* feat   = (const float*)d_in[0];
    const float* counts = (const float*)d_in[1];
    // d_in[2] total_count: ranks invariant under positive rescale -> unused
    const float* proto  = (const float*)d_in[3];
    const float* zs     = (const float*)d_in[4];
    const float* temp   = (const float*)d_in[5];
    const float* W1     = (const float*)d_in[6];
    const float* b1     = (const float*)d_in[7];
    const float* W2     = (const float*)d_in[8];
    const float* b2     = (const float*)d_in[9];

    char* ws = (char*)d_ws;
    // workspace layout (bytes), total 5,120,768
    float* zw            = (float*)(ws + 0);          // 1024 f32
    float* zwsum         = (float*)(ws + 4096);       // 1 f32
    float* invf          = (float*)(ws + 4352);       // 128 f32
    float* invp          = (float*)(ws + 4864);       // 1024 f32
    float* fp            = (float*)(ws + 8960);       // 128*512 f32
    float* dotraw        = (float*)(ws + 271104);     // 128*1024 f32
    float* hsp           = (float*)(ws + 795392);     // 2*128*1024 f32
    unsigned short* feat_bf  = (unsigned short*)(ws + 1843968);  // 128*512 bf16
    unsigned short* proto_bf = (unsigned short*)(ws + 1975040);  // 1024*512 bf16
    unsigned short* w1_bf    = (unsigned short*)(ws + 3023616);  // 512*1024 bf16
    unsigned short* ppbT     = (unsigned short*)(ws + 4072192);  // 512*1024 bf16

    hipMemsetAsync(zwsum, 0, 4, stream);

    prep_kernel<<<816, 256, 0, stream>>>(feat, counts, proto, zs, W1,
                                         feat_bf, proto_bf, w1_bf,
                                         zw, zwsum, invf, invp);
    gemm3_kernel<<<176, 256, 0, stream>>>(feat_bf, proto_bf, w1_bf, b1,
                                          fp, ppbT, dotraw);
    hs_kernel<<<256, 256, 0, stream>>>(fp, ppbT, W2, hsp);
    combine_kernel<<<128, 256, 0, stream>>>(dotraw, hsp, zw, zwsum, invf, invp,
                                            temp, b2, (float*)d_out);
}

// Round 2
// 101.156 us; speedup vs baseline: 1.6084x; 1.6084x over previous
//
#include <hip/hip_runtime.h>
#include <hip/hip_bf16.h>

// B=128, V=1024, D=512.
// 3 kernels:
//   gemm_prep: blocks [0,176) three bf16 MFMA GEMMs (f32 loaded, cvt in-reg, prefetch-pipelined):
//                fpT   = (feat @ Wf^T)^T          (512x128 f32, TRANSPOSED for hs scalar loads)
//                ppbT  = Wp @ proto^T + b1        (512x1024 bf16)
//                dotraw= feat @ proto^T           (128x1024 f32)
//              blocks [176,192) zipf ranks -> zw ; blocks [192,480) row inv-norms
//   hs:        hs[ks][b][v] partial = sum_{k in ks} relu(fpT[k][b]+ppbT[k][v])*W2[k]
//              b-tile 8, v-tile 512, ksplit 16 -> 512 blocks (2/CU)
//   combine:   w = (zw/sum(zw))*(1+sim)*sigmoid(sum_ks hs + b2); softmax over v

typedef __attribute__((ext_vector_type(8))) short bhalf8;
typedef __attribute__((ext_vector_type(4))) float f32x4;

static __device__ __forceinline__ unsigned short f2bf(float x) {
    union { __hip_bfloat16 h; unsigned short u; } cv;
    cv.h = __float2bfloat16(x);
    return cv.u;
}

static __device__ __forceinline__ int4 pack_bf16_8(float4 x, float4 y) {
    union { ushort u[8]; int4 v; } r;
    r.u[0] = f2bf(x.x); r.u[1] = f2bf(x.y); r.u[2] = f2bf(x.z); r.u[3] = f2bf(x.w);
    r.u[4] = f2bf(y.x); r.u[5] = f2bf(y.y); r.u[6] = f2bf(y.z); r.u[7] = f2bf(y.w);
    return r.v;
}

// ---------------- gemm_prep ----------------
__global__ __launch_bounds__(256) void gemm_prep_kernel(
    const float* __restrict__ feat, const float* __restrict__ counts,
    const float* __restrict__ proto, const float* __restrict__ zs,
    const float* __restrict__ W1, const float* __restrict__ b1,
    float* __restrict__ fpT, unsigned short* __restrict__ ppbT,
    float* __restrict__ dotraw,
    float* __restrict__ zw, float* __restrict__ invf, float* __restrict__ invp)
{
    int bx = blockIdx.x, tid = threadIdx.x;

    if (bx >= 176) {
        if (bx < 192) {
            // zipf: block handles 64 i's; 4 threads per i scan quarters of j
            __shared__ float cn[1024];
            ((float4*)cn)[tid] = ((const float4*)counts)[tid];
            __syncthreads();
            int il = tid >> 2, q = tid & 3;
            int i = (bx - 176) * 64 + il;
            float ci = cn[i];
            int cnt = 0;
            int j0 = q * 256;
            for (int j = j0; j < j0 + 256; ++j) {
                float cj = cn[j];
                cnt += (cj > ci) ? 1 : 0;
                cnt += (cj == ci && j < i) ? 1 : 0;  // stable tie-break
            }
            cnt += __shfl_xor(cnt, 1);
            cnt += __shfl_xor(cnt, 2);
            if (q == 0) zw[i] = powf((float)(cnt + 1), -zs[0]);
        } else {
            // inverse L2 norms: 4 rows/block, 1 wave/row (0..127 feat, 128..1151 proto)
            int nb = bx - 192;
            int w = tid >> 6, lane = tid & 63;
            int row = nb * 4 + w;
            const float* src = (row < 128) ? (feat + (size_t)row * 512)
                                           : (proto + (size_t)(row - 128) * 512);
            const float4* rp = (const float4*)src;
            float4 a = rp[lane * 2], b = rp[lane * 2 + 1];
            float ss = a.x*a.x + a.y*a.y + a.z*a.z + a.w*a.w
                     + b.x*b.x + b.y*b.y + b.z*b.z + b.w*b.w;
            for (int o = 32; o; o >>= 1) ss += __shfl_xor(ss, o);
            if (lane == 0) {
                float inv = 1.0f / fmaxf(sqrtf(ss), 1e-12f);
                if (row < 128) invf[row] = inv; else invp[row - 128] = inv;
            }
        }
        return;
    }

    // ---- GEMM part: 64x64 tiles, BK=32, f32 global loads, cvt->bf16 in reg ----
    const float* A; const float* Bm;
    int lda, ldb, tm, tn, mode;  // mode 0: fpT (transposed f32), 1: ppbT (bf16+bias), 2: dotraw
    if (bx < 16) {
        A = feat; lda = 512; Bm = W1; ldb = 1024; mode = 0;  // B rows = Wf rows (first 512 cols)
        tm = bx >> 3; tn = bx & 7;
    } else if (bx < 144) {
        int t = bx - 16;
        A = W1 + 512; lda = 1024; Bm = proto; ldb = 512; mode = 1;  // A rows = Wp rows
        tm = t >> 4; tn = t & 15;
    } else {
        int t = bx - 144;
        A = feat; lda = 512; Bm = proto; ldb = 512; mode = 2;
        tm = t >> 4; tn = t & 15;
    }

    __shared__ unsigned short As[64 * 40];  // +8 halfs pad: 2-way alias max (free)
    __shared__ unsigned short Bs[64 * 40];

    int r = tid >> 2, kq = (tid & 3) * 8;
    int wave = tid >> 6, lane = tid & 63;
    int fr = lane & 15, quad = lane >> 4;

    const float* Ag = A + (size_t)(tm * 64 + r) * lda + kq;
    const float* Bg = Bm + (size_t)(tn * 64 + r) * ldb + kq;

    float4 a0 = *(const float4*)(Ag),     a1 = *(const float4*)(Ag + 4);
    float4 g0 = *(const float4*)(Bg),     g1 = *(const float4*)(Bg + 4);

    f32x4 acc0 = {0.f, 0.f, 0.f, 0.f};
    f32x4 acc1 = acc0, acc2 = acc0, acc3 = acc0;

    for (int kc = 0; kc < 512; kc += 32) {
        __syncthreads();
        *(int4*)&As[r * 40 + kq] = pack_bf16_8(a0, a1);
        *(int4*)&Bs[r * 40 + kq] = pack_bf16_8(g0, g1);
        __syncthreads();
        if (kc + 32 < 512) {  // prefetch next tile; overlaps ds_read+MFMA below
            a0 = *(const float4*)(Ag + kc + 32); a1 = *(const float4*)(Ag + kc + 36);
            g0 = *(const float4*)(Bg + kc + 32); g1 = *(const float4*)(Bg + kc + 36);
        }
        bhalf8 af  = *(const bhalf8*)&As[(wave * 16 + fr) * 40 + quad * 8];
        bhalf8 bf0 = *(const bhalf8*)&Bs[(fr) * 40 + quad * 8];
        bhalf8 bf1 = *(const bhalf8*)&Bs[(16 + fr) * 40 + quad * 8];
        bhalf8 bf2 = *(const bhalf8*)&Bs[(32 + fr) * 40 + quad * 8];
        bhalf8 bf3 = *(const bhalf8*)&Bs[(48 + fr) * 40 + quad * 8];
        acc0 = __builtin_amdgcn_mfma_f32_16x16x32_bf16(af, bf0, acc0, 0, 0, 0);
        acc1 = __builtin_amdgcn_mfma_f32_16x16x32_bf16(af, bf1, acc1, 0, 0, 0);
        acc2 = __builtin_amdgcn_mfma_f32_16x16x32_bf16(af, bf2, acc2, 0, 0, 0);
        acc3 = __builtin_amdgcn_mfma_f32_16x16x32_bf16(af, bf3, acc3, 0, 0, 0);
    }

    // C/D layout: col = lane&15, row = quad*4 + reg  [m89/m91]
    int m0 = tm * 64 + wave * 16 + quad * 4;
    int n0 = tn * 64 + fr;
    f32x4 accs[4] = {acc0, acc1, acc2, acc3};
    if (mode == 0) {
        // store transposed: fpT[k(=n)][b(=m)], ld 128
        for (int j = 0; j < 4; ++j)
            for (int rr = 0; rr < 4; ++rr)
                fpT[(size_t)(n0 + j * 16) * 128 + m0 + rr] = accs[j][rr];
    } else if (mode == 1) {
        float bv4[4];
        for (int rr = 0; rr < 4; ++rr) bv4[rr] = b1[m0 + rr];
        for (int j = 0; j < 4; ++j)
            for (int rr = 0; rr < 4; ++rr)
                ppbT[(size_t)(m0 + rr) * 1024 + n0 + j * 16] = f2bf(accs[j][rr] + bv4[rr]);
    } else {
        for (int j = 0; j < 4; ++j)
            for (int rr = 0; rr < 4; ++rr)
                dotraw[(size_t)(m0 + rr) * 1024 + n0 + j * 16] = accs[j][rr];
    }
}

// ---------------- hs: partial[ks][b][v] = sum_{k in seg} relu(fpT[k][b]+ppbT[k][v])*W2[k] ----
// grid 512 = bg(16, b-tile 8) x vh(2, v-tile 512) x ks(16, 32 k's each); 256 thr, 2 v/thread
__global__ __launch_bounds__(256) void hs_kernel(
    const float* __restrict__ fpT, const unsigned short* __restrict__ ppbT,
    const float* __restrict__ W2, float* __restrict__ hsp)
{
    int bx = blockIdx.x, tid = threadIdx.x;
    int bg = bx & 15, vh = (bx >> 4) & 1, ks = bx >> 5;
    int b0 = bg * 8, v = vh * 512 + tid * 2, k0 = ks * 32;

    float acc[8][2] = {};
    #pragma unroll 8
    for (int kk = 0; kk < 32; ++kk) {
        int k = k0 + kk;
        unsigned int u = *(const unsigned int*)(ppbT + (size_t)k * 1024 + v);
        float px = __uint_as_float(u << 16);
        float py = __uint_as_float(u & 0xffff0000u);
        float w2k = W2[k];                                      // uniform -> s_load
        float4 fa = *(const float4*)(fpT + (size_t)k * 128 + b0);      // uniform
        float4 fb = *(const float4*)(fpT + (size_t)k * 128 + b0 + 4);  // uniform
        float f[8] = {fa.x, fa.y, fa.z, fa.w, fb.x, fb.y, fb.z, fb.w};
        #pragma unroll
        for (int i = 0; i < 8; ++i) {
            acc[i][0] += fmaxf(f[i] + px, 0.f) * w2k;
            acc[i][1] += fmaxf(f[i] + py, 0.f) * w2k;
        }
    }
    float* o = hsp + ((size_t)ks * 128 + b0) * 1024 + v;
    #pragma unroll
    for (int i = 0; i < 8; ++i)
        *(float2*)(o + (size_t)i * 1024) = make_float2(acc[i][0], acc[i][1]);
}

// ---------------- combine + softmax: one block per b ----------------
__global__ __launch_bounds__(256) void combine_kernel(
    const float* __restrict__ dotraw, const float* __restrict__ hsp,
    const float* __restrict__ zw,
    const float* __restrict__ invf, const float* __restrict__ invp,
    const float* __restrict__ temp, const float* __restrict__ b2,
    float* __restrict__ out)
{
    int b = blockIdx.x, tid = threadIdx.x;
    int wave = tid >> 6, lane = tid & 63;
    int v = tid * 4;
    __shared__ float red[4];

    float it  = invf[b] / fmaxf(temp[0], 1e-4f);
    float b2v = b2[0];

    float4 zw4 = *(const float4*)(zw + v);
    float4 dr  = *(const float4*)(dotraw + (size_t)b * 1024 + v);
    float4 ip4 = *(const float4*)(invp + v);

    // sum 16 hs partial planes
    float4 h = {0.f, 0.f, 0.f, 0.f};
    #pragma unroll
    for (int s = 0; s < 16; ++s) {
        float4 hp = *(const float4*)(hsp + ((size_t)s * 128 + b) * 1024 + v);
        h.x += hp.x; h.y += hp.y; h.z += hp.z; h.w += hp.w;
    }

    // local zw-sum reduction (every block reads all of zw anyway)
    float zs4 = zw4.x + zw4.y + zw4.z + zw4.w;
    for (int o = 32; o; o >>= 1) zs4 += __shfl_xor(zs4, o);
    if (lane == 0) red[wave] = zs4;
    __syncthreads();
    float izw = 1.0f / fmaxf(red[0] + red[1] + red[2] + red[3], 1e-8f);
    __syncthreads();

    float4 w;
    {
        float s0 = dr.x * it * ip4.x, s1 = dr.y * it * ip4.y;
        float s2 = dr.z * it * ip4.z, s3 = dr.w * it * ip4.w;
        float g0 = h.x + b2v, g1 = h.y + b2v, g2 = h.z + b2v, g3 = h.w + b2v;
        w.x = (zw4.x * izw) * (1.0f + s0) * (1.0f / (1.0f + expf(-g0)));
        w.y = (zw4.y * izw) * (1.0f + s1) * (1.0f / (1.0f + expf(-g1)));
        w.z = (zw4.z * izw) * (1.0f + s2) * (1.0f / (1.0f + expf(-g2)));
        w.w = (zw4.w * izw) * (1.0f + s3) * (1.0f / (1.0f + expf(-g3)));
    }

    float mx = fmaxf(fmaxf(w.x, w.y), fmaxf(w.z, w.w));
    for (int o = 32; o; o >>= 1) mx = fmaxf(mx, __shfl_xor(mx, o));
    if (lane == 0) red[wave] = mx;
    __syncthreads();
    mx = fmaxf(fmaxf(red[0], red[1]), fmaxf(red[2], red[3]));
    __syncthreads();

    float4 e;
    e.x = expf(w.x - mx); e.y = expf(w.y - mx);
    e.z = expf(w.z - mx); e.w = expf(w.w - mx);
    float sm = e.x + e.y + e.z + e.w;
    for (int o = 32; o; o >>= 1) sm += __shfl_xor(sm, o);
    if (lane == 0) red[wave] = sm;
    __syncthreads();
    float inv = 1.0f / (red[0] + red[1] + red[2] + red[3]);

    float4 r4;
    r4.x = e.x * inv; r4.y = e.y * inv; r4.z = e.z * inv; r4.w = e.w * inv;
    *(float4*)(out + (size_t)b * 1024 + v) = r4;
}

// ---------------- launch ----------------
extern "C" void kernel_launch(void* const* d_in, const int* in_sizes, int n_in,
                              void* d_out, int out_size, void* d_ws, size_t ws_size,
                              hipStream_t stream) {
    const float* feat   = (const float*)d_in[0];
    const float* counts = (const float*)d_in[1];
    // d_in[2] total_count: ranks invariant under positive rescale -> unused
    const float* proto  = (const float*)d_in[3];
    const float* zs     = (const float*)d_in[4];
    const float* temp   = (const float*)d_in[5];
    const float* W1     = (const float*)d_in[6];
    const float* b1     = (const float*)d_in[7];
    const float* W2     = (const float*)d_in[8];
    const float* b2     = (const float*)d_in[9];

    char* ws = (char*)d_ws;
    // workspace layout (bytes), total 10,232,320
    float* zw     = (float*)(ws + 0);              // 1024 f32
    float* invf   = (float*)(ws + 4096);           // 128 f32
    float* invp   = (float*)(ws + 4608);           // 1024 f32
    float* fpT    = (float*)(ws + 8704);           // 512x128 f32 (transposed fp)
    float* dotraw = (float*)(ws + 270848);         // 128x1024 f32
    unsigned short* ppbT = (unsigned short*)(ws + 795136);  // 512x1024 bf16
    float* hsp    = (float*)(ws + 1843712);        // 16 x 128x1024 f32 partials

    gemm_prep_kernel<<<480, 256, 0, stream>>>(feat, counts, proto, zs, W1, b1,
                                              fpT, ppbT, dotraw, zw, invf, invp);
    hs_kernel<<<512, 256, 0, stream>>>(fpT, ppbT, W2, hsp);
    combine_kernel<<<128, 256, 0, stream>>>(dotraw, hsp, zw, invf, invp,
                                            temp, b2, (float*)d_out);
}

// Round 3
// 100.408 us; speedup vs baseline: 1.6204x; 1.0075x over previous
//
#include <hip/hip_runtime.h>
#include <hip/hip_bf16.h>

// B=128, V=1024, D=512.
// 3 kernels:
//   gemm_prep: blocks [0,176) three bf16 MFMA GEMMs, BK=64, LDS double-buffered
//              (one barrier/iter), f32 loaded + cvt in-reg:
//                fpT   = (feat @ Wf^T)^T          (512x128 f32, transposed for hs)
//                ppbT  = Wp @ proto^T + b1        (512x1024 bf16)
//                dotraw= feat @ proto^T           (128x1024 f32)
//              blocks [176,192) zipf ranks -> zw ; blocks [192,480) row inv-norms
//   hs:        hs[ks][b][v] = sum_{k in seg32} relu(fpT[k][b]+ppbT[k][v])*W2[k]
//              b-tile 4, v-tile 512, ksplit 16 -> 1024 blocks (4/CU, 16 waves/CU)
//   combine:   1024 thr/block, 1 v/thread; w = (zw/sum zw)*(1+sim)*sigmoid(.); softmax

typedef __attribute__((ext_vector_type(8))) short bhalf8;
typedef __attribute__((ext_vector_type(4))) float f32x4;

static __device__ __forceinline__ unsigned short f2bf(float x) {
    union { __hip_bfloat16 h; unsigned short u; } cv;
    cv.h = __float2bfloat16(x);
    return cv.u;
}

static __device__ __forceinline__ int4 pack_bf16_8(float4 x, float4 y) {
    union { ushort u[8]; int4 v; } r;
    r.u[0] = f2bf(x.x); r.u[1] = f2bf(x.y); r.u[2] = f2bf(x.z); r.u[3] = f2bf(x.w);
    r.u[4] = f2bf(y.x); r.u[5] = f2bf(y.y); r.u[6] = f2bf(y.z); r.u[7] = f2bf(y.w);
    return r.v;
}

// ---------------- gemm_prep ----------------
__global__ __launch_bounds__(256) void gemm_prep_kernel(
    const float* __restrict__ feat, const float* __restrict__ counts,
    const float* __restrict__ proto, const float* __restrict__ zs,
    const float* __restrict__ W1, const float* __restrict__ b1,
    float* __restrict__ fpT, unsigned short* __restrict__ ppbT,
    float* __restrict__ dotraw,
    float* __restrict__ zw, float* __restrict__ invf, float* __restrict__ invp)
{
    int bx = blockIdx.x, tid = threadIdx.x;

    if (bx >= 176) {
        if (bx < 192) {
            // zipf: 64 i's per block; 4 threads per i scan quarters of j
            __shared__ float cn[1024];
            ((float4*)cn)[tid] = ((const float4*)counts)[tid];
            __syncthreads();
            int il = tid >> 2, q = tid & 3;
            int i = (bx - 176) * 64 + il;
            float ci = cn[i];
            int cnt = 0;
            int j0 = q * 256;
            for (int j = j0; j < j0 + 256; ++j) {
                float cj = cn[j];
                cnt += (cj > ci) ? 1 : 0;
                cnt += (cj == ci && j < i) ? 1 : 0;  // stable tie-break
            }
            cnt += __shfl_xor(cnt, 1);
            cnt += __shfl_xor(cnt, 2);
            if (q == 0) zw[i] = powf((float)(cnt + 1), -zs[0]);
        } else {
            // inverse L2 norms: 4 rows/block, 1 wave/row
            int nb = bx - 192;
            int w = tid >> 6, lane = tid & 63;
            int row = nb * 4 + w;
            const float* src = (row < 128) ? (feat + (size_t)row * 512)
                                           : (proto + (size_t)(row - 128) * 512);
            const float4* rp = (const float4*)src;
            float4 a = rp[lane * 2], b = rp[lane * 2 + 1];
            float ss = a.x*a.x + a.y*a.y + a.z*a.z + a.w*a.w
                     + b.x*b.x + b.y*b.y + b.z*b.z + b.w*b.w;
            for (int o = 32; o; o >>= 1) ss += __shfl_xor(ss, o);
            if (lane == 0) {
                float inv = 1.0f / fmaxf(sqrtf(ss), 1e-12f);
                if (row < 128) invf[row] = inv; else invp[row - 128] = inv;
            }
        }
        return;
    }

    // ---- GEMM: 64x64 tiles, BK=64, double-buffered LDS, one barrier/iter ----
    const float* A; const float* Bm;
    int lda, ldb, tm, tn, mode;  // 0: fpT (f32 transposed), 1: ppbT (bf16+bias), 2: dotraw
    if (bx < 16) {
        A = feat; lda = 512; Bm = W1; ldb = 1024; mode = 0;
        tm = bx >> 3; tn = bx & 7;
    } else if (bx < 144) {
        int t = bx - 16;
        A = W1 + 512; lda = 1024; Bm = proto; ldb = 512; mode = 1;
        tm = t >> 4; tn = t & 15;
    } else {
        int t = bx - 144;
        A = feat; lda = 512; Bm = proto; ldb = 512; mode = 2;
        tm = t >> 4; tn = t & 15;
    }

    __shared__ unsigned short As[2][64 * 72];  // stride 72 halfs: 2-way alias max (free)
    __shared__ unsigned short Bs[2][64 * 72];

    int r = tid >> 2, kq = (tid & 3) * 16;   // row 0..63, k-offset {0,16,32,48} halfs
    int wave = tid >> 6, lane = tid & 63;
    int fr = lane & 15, quad = lane >> 4;

    const float* Ag = A + (size_t)(tm * 64 + r) * lda + kq;
    const float* Bg = Bm + (size_t)(tn * 64 + r) * ldb + kq;

    float4 a0 = *(const float4*)(Ag),      a1 = *(const float4*)(Ag + 4);
    float4 a2 = *(const float4*)(Ag + 8),  a3 = *(const float4*)(Ag + 12);
    float4 g0 = *(const float4*)(Bg),      g1 = *(const float4*)(Bg + 4);
    float4 g2 = *(const float4*)(Bg + 8),  g3 = *(const float4*)(Bg + 12);

    f32x4 acc0 = {0.f, 0.f, 0.f, 0.f};
    f32x4 acc1 = acc0, acc2 = acc0, acc3 = acc0;

    for (int kc = 0; kc < 512; kc += 64) {
        int p = (kc >> 6) & 1;
        *(int4*)&As[p][r * 72 + kq]     = pack_bf16_8(a0, a1);
        *(int4*)&As[p][r * 72 + kq + 8] = pack_bf16_8(a2, a3);
        *(int4*)&Bs[p][r * 72 + kq]     = pack_bf16_8(g0, g1);
        *(int4*)&Bs[p][r * 72 + kq + 8] = pack_bf16_8(g2, g3);
        __syncthreads();
        if (kc + 64 < 512) {  // prefetch next tile into regs; overlaps ds_read+MFMA
            const float* An = Ag + kc + 64;
            const float* Bn = Bg + kc + 64;
            a0 = *(const float4*)(An);     a1 = *(const float4*)(An + 4);
            a2 = *(const float4*)(An + 8); a3 = *(const float4*)(An + 12);
            g0 = *(const float4*)(Bn);     g1 = *(const float4*)(Bn + 4);
            g2 = *(const float4*)(Bn + 8); g3 = *(const float4*)(Bn + 12);
        }
        #pragma unroll
        for (int s = 0; s < 2; ++s) {
            int ko = s * 32 + quad * 8;
            bhalf8 af  = *(const bhalf8*)&As[p][(wave * 16 + fr) * 72 + ko];
            bhalf8 bf0 = *(const bhalf8*)&Bs[p][(fr) * 72 + ko];
            bhalf8 bf1 = *(const bhalf8*)&Bs[p][(16 + fr) * 72 + ko];
            bhalf8 bf2 = *(const bhalf8*)&Bs[p][(32 + fr) * 72 + ko];
            bhalf8 bf3 = *(const bhalf8*)&Bs[p][(48 + fr) * 72 + ko];
            acc0 = __builtin_amdgcn_mfma_f32_16x16x32_bf16(af, bf0, acc0, 0, 0, 0);
            acc1 = __builtin_amdgcn_mfma_f32_16x16x32_bf16(af, bf1, acc1, 0, 0, 0);
            acc2 = __builtin_amdgcn_mfma_f32_16x16x32_bf16(af, bf2, acc2, 0, 0, 0);
            acc3 = __builtin_amdgcn_mfma_f32_16x16x32_bf16(af, bf3, acc3, 0, 0, 0);
        }
        // NOTE: single barrier per iter is safe — a wave only rewrites buf[p]
        // two iters later, after passing the next barrier, by which time all
        // waves have consumed their ds_reads of buf[p] (waitcnt before MFMA).
    }

    // C/D layout: col = lane&15, row = quad*4 + reg  [m89/m91]
    int m0 = tm * 64 + wave * 16 + quad * 4;
    int n0 = tn * 64 + fr;
    f32x4 accs[4] = {acc0, acc1, acc2, acc3};
    if (mode == 0) {
        for (int j = 0; j < 4; ++j)
            for (int rr = 0; rr < 4; ++rr)
                fpT[(size_t)(n0 + j * 16) * 128 + m0 + rr] = accs[j][rr];
    } else if (mode == 1) {
        float bv4[4];
        for (int rr = 0; rr < 4; ++rr) bv4[rr] = b1[m0 + rr];
        for (int j = 0; j < 4; ++j)
            for (int rr = 0; rr < 4; ++rr)
                ppbT[(size_t)(m0 + rr) * 1024 + n0 + j * 16] = f2bf(accs[j][rr] + bv4[rr]);
    } else {
        for (int j = 0; j < 4; ++j)
            for (int rr = 0; rr < 4; ++rr)
                dotraw[(size_t)(m0 + rr) * 1024 + n0 + j * 16] = accs[j][rr];
    }
}

// ---------------- hs: partial[ks][b][v] = sum_{k in seg} relu(fpT[k][b]+ppbT[k][v])*W2[k] ---
// grid 1024 = bg(32, b-tile 4) x vh(2, v-tile 512) x ks(16, 32 k's); 256 thr, 2 v/thread
__global__ __launch_bounds__(256) void hs_kernel(
    const float* __restrict__ fpT, const unsigned short* __restrict__ ppbT,
    const float* __restrict__ W2, float* __restrict__ hsp)
{
    int bx = blockIdx.x, tid = threadIdx.x;
    int bg = bx & 31, vh = (bx >> 5) & 1, ks = bx >> 6;
    int b0 = bg * 4, v = vh * 512 + tid * 2, k0 = ks * 32;

    float acc[4][2] = {};
    #pragma unroll 8
    for (int kk = 0; kk < 32; ++kk) {
        int k = k0 + kk;
        unsigned int u = *(const unsigned int*)(ppbT + (size_t)k * 1024 + v);
        float px = __uint_as_float(u << 16);
        float py = __uint_as_float(u & 0xffff0000u);
        float w2k = W2[k];                                        // uniform -> s_load
        float4 fa = *(const float4*)(fpT + (size_t)k * 128 + b0); // uniform
        float f[4] = {fa.x, fa.y, fa.z, fa.w};
        #pragma unroll
        for (int i = 0; i < 4; ++i) {
            acc[i][0] += fmaxf(f[i] + px, 0.f) * w2k;
            acc[i][1] += fmaxf(f[i] + py, 0.f) * w2k;
        }
    }
    float* o = hsp + ((size_t)ks * 128 + b0) * 1024 + v;
    #pragma unroll
    for (int i = 0; i < 4; ++i)
        *(float2*)(o + (size_t)i * 1024) = make_float2(acc[i][0], acc[i][1]);
}

// ---------------- combine + softmax: one block per b, 1024 threads (1 v each) --------------
__global__ __launch_bounds__(1024) void combine_kernel(
    const float* __restrict__ dotraw, const float* __restrict__ hsp,
    const float* __restrict__ zw,
    const float* __restrict__ invf, const float* __restrict__ invp,
    const float* __restrict__ temp, const float* __restrict__ b2,
    float* __restrict__ out)
{
    int b = blockIdx.x, tid = threadIdx.x;
    int wave = tid >> 6, lane = tid & 63;
    int v = tid;
    __shared__ float red[16];

    float it  = invf[b] / fmaxf(temp[0], 1e-4f);
    float b2v = b2[0];

    float zwv = zw[v];
    float dr  = dotraw[(size_t)b * 1024 + v];
    float ipv = invp[v];

    float h = 0.f;
    #pragma unroll
    for (int s = 0; s < 16; ++s)
        h += hsp[((size_t)s * 128 + b) * 1024 + v];

    // zw-sum (recomputed locally; cheaper than an extra memset+atomic pass)
    float zs4 = zwv;
    for (int o = 32; o; o >>= 1) zs4 += __shfl_xor(zs4, o);
    if (lane == 0) red[wave] = zs4;
    __syncthreads();
    float zsum = 0.f;
    #pragma unroll
    for (int i = 0; i < 16; ++i) zsum += red[i];
    float izw = 1.0f / fmaxf(zsum, 1e-8f);
    __syncthreads();

    float sim = dr * it * ipv;
    float g = h + b2v;
    float w = (zwv * izw) * (1.0f + sim) * (1.0f / (1.0f + expf(-g)));

    float mx = w;
    for (int o = 32; o; o >>= 1) mx = fmaxf(mx, __shfl_xor(mx, o));
    if (lane == 0) red[wave] = mx;
    __syncthreads();
    mx = red[0];
    #pragma unroll
    for (int i = 1; i < 16; ++i) mx = fmaxf(mx, red[i]);
    __syncthreads();

    float e = expf(w - mx);
    float sm = e;
    for (int o = 32; o; o >>= 1) sm += __shfl_xor(sm, o);
    if (lane == 0) red[wave] = sm;
    __syncthreads();
    float tot = 0.f;
    #pragma unroll
    for (int i = 0; i < 16; ++i) tot += red[i];

    out[(size_t)b * 1024 + v] = e / tot;
}

// ---------------- launch ----------------
extern "C" void kernel_launch(void* const* d_in, const int* in_sizes, int n_in,
                              void* d_out, int out_size, void* d_ws, size_t ws_size,
                              hipStream_t stream) {
    const float* feat   = (const float*)d_in[0];
    const float* counts = (const float*)d_in[1];
    // d_in[2] total_count: ranks invariant under positive rescale -> unused
    const float* proto  = (const float*)d_in[3];
    const float* zs     = (const float*)d_in[4];
    const float* temp   = (const float*)d_in[5];
    const float* W1     = (const float*)d_in[6];
    const float* b1     = (const float*)d_in[7];
    const float* W2     = (const float*)d_in[8];
    const float* b2     = (const float*)d_in[9];

    char* ws = (char*)d_ws;
    float* zw     = (float*)(ws + 0);              // 1024 f32
    float* invf   = (float*)(ws + 4096);           // 128 f32
    float* invp   = (float*)(ws + 4608);           // 1024 f32
    float* fpT    = (float*)(ws + 8704);           // 512x128 f32 (transposed fp)
    float* dotraw = (float*)(ws + 270848);         // 128x1024 f32
    unsigned short* ppbT = (unsigned short*)(ws + 795136);  // 512x1024 bf16
    float* hsp    = (float*)(ws + 1843712);        // 16 x 128x1024 f32 partials

    gemm_prep_kernel<<<480, 256, 0, stream>>>(feat, counts, proto, zs, W1, b1,
                                              fpT, ppbT, dotraw, zw, invf, invp);
    hs_kernel<<<1024, 256, 0, stream>>>(fpT, ppbT, W2, hsp);
    combine_kernel<<<128, 1024, 0, stream>>>(dotraw, hsp, zw, invf, invp,
                                             temp, b2, (float*)d_out);
}